// Round 2
// baseline (230.982 us; speedup 1.0000x reference)
//
#include <hip/hip_runtime.h>
#include <math.h>

#define N_NODES 40000
#define N_EDGES 320000
#define F_IN 128
#define NHEAD 4
#define HC 256
#define NOUT 64
#define SLOTCAP 40   // max degree capacity; P(Poisson(8) >= 40) ~ 1e-18 per node

typedef __attribute__((ext_vector_type(8))) __bf16 bf16x8;
typedef __attribute__((ext_vector_type(4))) float f32x4;

static __device__ __forceinline__ unsigned short f2bf(float f) {
    union { float f; unsigned u; } v; v.f = f;
    unsigned r = v.u + 0x7FFFu + ((v.u >> 16) & 1u);
    return (unsigned short)(r >> 16);
}
static __device__ __forceinline__ float bf2f(unsigned short s) {
    union { unsigned u; float f; } v; v.u = ((unsigned)s) << 16;
    return v.f;
}

// ---------------- prep: weight converts + zero cursor/ticket/bnacc --------
__global__ __launch_bounds__(256) void prep_kernel(const float* __restrict__ W1,
                                                   const float* __restrict__ W2,
                                                   const float* __restrict__ linW,
                                                   unsigned short* __restrict__ W1t,
                                                   unsigned short* __restrict__ W2t,
                                                   unsigned short* __restrict__ linWt,
                                                   int* __restrict__ zero_ints,
                                                   float* __restrict__ bnacc) {
    int b = blockIdx.x, tid = threadIdx.x;
    if (b < 128) {
        int t = b * 256 + tid;
        int k = t >> 8, n = t & 255;
        W1t[n * 128 + k] = f2bf(W1[t]);
    } else if (b < 384) {
        int t = (b - 128) * 256 + tid;
        int k = t >> 8, n = t & 255;
        W2t[n * 256 + k] = f2bf(W2[t]);
    } else if (b < 448) {
        int t = (b - 384) * 256 + tid;
        int k = t >> 6, n = t & 63;
        linWt[n * 256 + k] = f2bf(linW[t]);
    } else if (b < 488) {
        int i = (b - 448) * 1024 + tid * 4;
        if (i < 40004) *(int4*)(zero_ints + i) = make_int4(0, 0, 0, 0);
    } else {
        if (tid < 512) bnacc[tid] = 0.f;
    }
}

// ---------------- wide MFMA GEMM: 64 rows x 256 cols, dbuf LDS ------------
// AMODE 1: A = f32[M,K] (convert in staging)
// AMODE 3: A = bf16[M,K], elu(x*sc+shift) in staging (via __expf)
// SCATTER 1: blocks >= 625 instead do direct-slot CSR scatter
// LDS double-buffered: ONE barrier per K-step (write buf[k&1], sync, read;
// next iter writes the other buffer so the trailing barrier is unnecessary).
template <int AMODE, int SCATTER>
__global__ __launch_bounds__(256) void gemm_wide(const void* __restrict__ Aptr,
                                                 const unsigned short* __restrict__ Bt,
                                                 const float* __restrict__ sc,
                                                 unsigned short* __restrict__ Cb,
                                                 const float* __restrict__ asrc,
                                                 const float* __restrict__ adst,
                                                 float* __restrict__ es,
                                                 float* __restrict__ ed,
                                                 int K,
                                                 const int* __restrict__ ei,
                                                 int* __restrict__ cursor,
                                                 int* __restrict__ esorted) {
    __shared__ unsigned short As[2][64 * 32];
    __shared__ unsigned short Bs[2][256 * 32];
    int tid = threadIdx.x;
    if (SCATTER && blockIdx.x >= N_NODES / 64) {
        int e = (blockIdx.x - N_NODES / 64) * 256 + tid;
        if (e < N_EDGES) {
            int d = ei[N_EDGES + e];
            int s = ei[e];
            int pos = atomicAdd(&cursor[d], 1);
            esorted[d * SLOTCAP + pos] = s;
        }
        return;
    }
    int row0 = blockIdx.x * 64;
    int w = tid >> 6, lane = tid & 63;
    int quad = lane >> 4, l16 = lane & 15;
    f32x4 acc[4][4];
#pragma unroll
    for (int mi = 0; mi < 4; ++mi)
#pragma unroll
        for (int ni = 0; ni < 4; ++ni) acc[mi][ni] = (f32x4){0.f, 0.f, 0.f, 0.f};

    int srow = tid >> 2, schunk = (tid & 3) * 8;
    int brow = tid >> 1, bchunk = (tid & 1) * 16;

    float4 pa0, pa1;
    int4 pai;
    int4 pb[4];
    if (AMODE == 1) {
        const float* Af = (const float*)Aptr;
        size_t base = (size_t)(row0 + srow) * K + schunk;
        pa0 = *(const float4*)(Af + base);
        pa1 = *(const float4*)(Af + base + 4);
    } else {
        pai = *(const int4*)((const unsigned short*)Aptr + (size_t)(row0 + srow) * K + schunk);
    }
    {
        const unsigned short* s0 = Bt + (size_t)brow * K + bchunk;
        const unsigned short* s1 = Bt + (size_t)(128 + brow) * K + bchunk;
        pb[0] = *(const int4*)s0; pb[1] = *(const int4*)(s0 + 8);
        pb[2] = *(const int4*)s1; pb[3] = *(const int4*)(s1 + 8);
    }

    for (int kc = 0; kc < K; kc += 32) {
        int buf = (kc >> 5) & 1;
        union { int4 v; unsigned short u[8]; } aS;
        if (AMODE == 1) {
            aS.u[0] = f2bf(pa0.x); aS.u[1] = f2bf(pa0.y);
            aS.u[2] = f2bf(pa0.z); aS.u[3] = f2bf(pa0.w);
            aS.u[4] = f2bf(pa1.x); aS.u[5] = f2bf(pa1.y);
            aS.u[6] = f2bf(pa1.z); aS.u[7] = f2bf(pa1.w);
        } else {
            union { int4 v; unsigned short u[8]; } a;
            a.v = pai;
#pragma unroll
            for (int j = 0; j < 8; ++j) {
                int c = kc + schunk + j;
                float v = bf2f(a.u[j]) * sc[c] + sc[HC + c];
                v = v > 0.f ? v : (__expf(v) - 1.f);
                aS.u[j] = f2bf(v);
            }
        }
        int4 bS0 = pb[0], bS1 = pb[1], bS2 = pb[2], bS3 = pb[3];
        int kn = kc + 32;
        if (kn < K) {
            if (AMODE == 1) {
                const float* Af = (const float*)Aptr;
                size_t base = (size_t)(row0 + srow) * K + kn + schunk;
                pa0 = *(const float4*)(Af + base);
                pa1 = *(const float4*)(Af + base + 4);
            } else {
                pai = *(const int4*)((const unsigned short*)Aptr +
                                     (size_t)(row0 + srow) * K + kn + schunk);
            }
            const unsigned short* s0 = Bt + (size_t)brow * K + kn + bchunk;
            const unsigned short* s1 = Bt + (size_t)(128 + brow) * K + kn + bchunk;
            pb[0] = *(const int4*)s0; pb[1] = *(const int4*)(s0 + 8);
            pb[2] = *(const int4*)s1; pb[3] = *(const int4*)(s1 + 8);
        }
        *(int4*)(&As[buf][srow * 32 + schunk]) = aS.v;
        *(int4*)(&Bs[buf][brow * 32 + bchunk]) = bS0;
        *(int4*)(&Bs[buf][brow * 32 + bchunk + 8]) = bS1;
        *(int4*)(&Bs[buf][(128 + brow) * 32 + bchunk]) = bS2;
        *(int4*)(&Bs[buf][(128 + brow) * 32 + bchunk + 8]) = bS3;
        __syncthreads();
        bf16x8 af[4], bfr[4];
#pragma unroll
        for (int mi = 0; mi < 4; ++mi)
            af[mi] = *(const bf16x8*)(&As[buf][(mi * 16 + l16) * 32 + quad * 8]);
#pragma unroll
        for (int ni = 0; ni < 4; ++ni)
            bfr[ni] = *(const bf16x8*)(&Bs[buf][(w * 64 + ni * 16 + l16) * 32 + quad * 8]);
#pragma unroll
        for (int mi = 0; mi < 4; ++mi)
#pragma unroll
            for (int ni = 0; ni < 4; ++ni)
                acc[mi][ni] = __builtin_amdgcn_mfma_f32_16x16x32_bf16(
                    af[mi], bfr[ni], acc[mi][ni], 0, 0, 0);
        // no trailing barrier: next iteration writes the other LDS buffer
    }
#pragma unroll
    for (int mi = 0; mi < 4; ++mi)
#pragma unroll
        for (int ni = 0; ni < 4; ++ni) {
            int r0 = row0 + mi * 16 + quad * 4;
            int c = w * 64 + ni * 16 + l16;
#pragma unroll
            for (int r = 0; r < 4; ++r)
                Cb[(size_t)(r0 + r) * HC + c] = f2bf(acc[mi][ni][r]);
        }
    // fused attention scores (head = w), wave-local
    float as_v[4], ad_v[4];
#pragma unroll
    for (int ni = 0; ni < 4; ++ni) {
        int cl = ni * 16 + l16;
        as_v[ni] = asrc[w * 64 + cl];
        ad_v[ni] = adst[w * 64 + cl];
    }
#pragma unroll
    for (int mi = 0; mi < 4; ++mi)
#pragma unroll
        for (int r = 0; r < 4; ++r) {
            float s = 0.f, d = 0.f;
#pragma unroll
            for (int ni = 0; ni < 4; ++ni) {
                s += acc[mi][ni][r] * as_v[ni];
                d += acc[mi][ni][r] * ad_v[ni];
            }
#pragma unroll
            for (int off = 1; off < 16; off <<= 1) {
                s += __shfl_xor(s, off);
                d += __shfl_xor(d, off);
            }
            if (l16 == 0) {
                int row = row0 + mi * 16 + quad * 4 + r;
                es[(size_t)row * NHEAD + w] = s;
                ed[(size_t)row * NHEAD + w] = d;
            }
        }
}

// ------- softmax + aggregation: 2 nodes/wave, bf16 gather (16B/lane) ------
// Layer-1 path (JK handled by the fused layer-2 kernel below).
// NOTE: do NOT fuse BN stats here. R10 (LDS f32 atomics: CAS storm, 421us)
// and R11 (5000-block global atomics: 5000-way contention, 537us) both
// catastrophically regressed this kernel. Stats need a few-block kernel.
__global__ __launch_bounds__(256) void aggregate_kernel(const unsigned short* __restrict__ h,
                                                        const float* __restrict__ es,
                                                        const float* __restrict__ ed,
                                                        const int* __restrict__ deg,
                                                        const int* __restrict__ esorted,
                                                        const float* __restrict__ bias,
                                                        unsigned short* __restrict__ outb) {
    int tid = threadIdx.x;
    int wave = tid >> 6, lane = tid & 63;
    int half = lane >> 5, l = lane & 31;       // 2 nodes per wave, 32 lanes each
    int node = blockIdx.x * 8 + wave * 2 + half;
    int hh = l >> 3;                            // 8 channels/lane -> head = l>>3
    float edv = ed[node * NHEAD + hh];
    int d = deg[node];
    int beg = node * SLOTCAP;
    float dsum = 0.f;
    float a[8] = {0.f, 0.f, 0.f, 0.f, 0.f, 0.f, 0.f, 0.f};
    for (int i = 0; i < d; i += 8) {
        int s[8];
        int4 hv[8];
        float ep[8];
#pragma unroll
        for (int j = 0; j < 8; ++j) {
            int slot = i + j;
            s[j] = esorted[beg + (slot < d ? slot : d - 1)];
        }
#pragma unroll
        for (int j = 0; j < 8; ++j)
            hv[j] = *(const int4*)(h + (size_t)s[j] * HC + l * 8);
#pragma unroll
        for (int j = 0; j < 8; ++j)
            ep[j] = es[s[j] * NHEAD + hh];
#pragma unroll
        for (int j = 0; j < 8; ++j) {
            float e = ep[j] + edv;
            e = e > 0.f ? e : 0.2f * e;
            float w = __expf(e);
            w = (i + j < d) ? w : 0.f;   // adding exact 0.0f: order-identical sums
            dsum += w;
            union { int4 v; unsigned short u[8]; } hu;
            hu.v = hv[j];
#pragma unroll
            for (int k = 0; k < 8; ++k) a[k] += w * bf2f(hu.u[k]);
        }
    }
    float inv = 1.f / (dsum + 1e-16f);
    float4 bv0 = *(const float4*)(bias + l * 8);
    float4 bv1 = *(const float4*)(bias + l * 8 + 4);
    float bb[8] = {bv0.x, bv0.y, bv0.z, bv0.w, bv1.x, bv1.y, bv1.z, bv1.w};
    union { int4 v; unsigned short u[8]; } o;
#pragma unroll
    for (int k = 0; k < 8; ++k) o.u[k] = f2bf(a[k] * inv + bb[k]);
    *(int4*)(outb + (size_t)node * HC + l * 8) = o.v;
}

// ------- layer-2 aggregation + JK max (BN+ELU recompute) + projection ------
// 512 threads = 8 waves = 16 nodes/block. jk rows parked in LDS (264-short
// padded stride keeps ds_read_b128 to <=4-way bank aliasing). GEMM phase:
// one 16x256 @ 256x64 MFMA tile on waves 0-3.
// h1p buffer eliminated: the JK branch recomputes elu(bn(h1agg)) from the
// h1agg row + bnsc (2KB, L2-hot) — deletes a 20.5MB global write from gemm2
// and one bf16 rounding on this path.
__global__ __launch_bounds__(512) void aggregate2_fused(const unsigned short* __restrict__ h,
                                                        const float* __restrict__ es,
                                                        const float* __restrict__ ed,
                                                        const int* __restrict__ deg,
                                                        const int* __restrict__ esorted,
                                                        const float* __restrict__ bias,
                                                        const unsigned short* __restrict__ h1agg,
                                                        const float* __restrict__ bnsc,
                                                        const unsigned short* __restrict__ linWt,
                                                        const float* __restrict__ linb,
                                                        float* __restrict__ out) {
    __shared__ unsigned short jkS[16 * 264];
    __shared__ unsigned short BsF[64 * 264];
    int tid = threadIdx.x;
    // stage linWt [64][256] -> BsF (512 threads x 32 shorts), overlaps agg
    {
        int n = tid >> 3, k0 = (tid & 7) * 32;
        const int4* src = (const int4*)(linWt + n * 256 + k0);
        int4 v0 = src[0], v1 = src[1], v2 = src[2], v3 = src[3];
        int4* dstp = (int4*)(&BsF[n * 264 + k0]);
        dstp[0] = v0; dstp[1] = v1; dstp[2] = v2; dstp[3] = v3;
    }
    int wave = tid >> 6, lane = tid & 63;
    int half = lane >> 5, l = lane & 31;       // 2 nodes per wave, 32 lanes each
    int nloc = wave * 2 + half;                // 0..15
    int node = blockIdx.x * 16 + nloc;
    int hh = l >> 3;
    float edv = ed[node * NHEAD + hh];
    int d = deg[node];
    int beg = node * SLOTCAP;
    float dsum = 0.f;
    float a[8] = {0.f, 0.f, 0.f, 0.f, 0.f, 0.f, 0.f, 0.f};
    for (int i = 0; i < d; i += 8) {
        int s[8];
        int4 hv[8];
        float ep[8];
#pragma unroll
        for (int j = 0; j < 8; ++j) {
            int slot = i + j;
            s[j] = esorted[beg + (slot < d ? slot : d - 1)];
        }
#pragma unroll
        for (int j = 0; j < 8; ++j)
            hv[j] = *(const int4*)(h + (size_t)s[j] * HC + l * 8);
#pragma unroll
        for (int j = 0; j < 8; ++j)
            ep[j] = es[s[j] * NHEAD + hh];
#pragma unroll
        for (int j = 0; j < 8; ++j) {
            float e = ep[j] + edv;
            e = e > 0.f ? e : 0.2f * e;
            float w = __expf(e);
            w = (i + j < d) ? w : 0.f;
            dsum += w;
            union { int4 v; unsigned short u[8]; } hu;
            hu.v = hv[j];
#pragma unroll
            for (int k = 0; k < 8; ++k) a[k] += w * bf2f(hu.u[k]);
        }
    }
    float inv = 1.f / (dsum + 1e-16f);
    float4 bv0 = *(const float4*)(bias + l * 8);
    float4 bv1 = *(const float4*)(bias + l * 8 + 4);
    float bb[8] = {bv0.x, bv0.y, bv0.z, bv0.w, bv1.x, bv1.y, bv1.z, bv1.w};
    union { int4 v; unsigned short u[8]; } o;
    {
        union { int4 v; unsigned short u[8]; } h1u;
        h1u.v = *(const int4*)(h1agg + (size_t)node * HC + l * 8);
        float4 s0 = *(const float4*)(bnsc + l * 8);
        float4 s1 = *(const float4*)(bnsc + l * 8 + 4);
        float4 t0 = *(const float4*)(bnsc + HC + l * 8);
        float4 t1 = *(const float4*)(bnsc + HC + l * 8 + 4);
        float scv[8] = {s0.x, s0.y, s0.z, s0.w, s1.x, s1.y, s1.z, s1.w};
        float shv[8] = {t0.x, t0.y, t0.z, t0.w, t1.x, t1.y, t1.z, t1.w};
#pragma unroll
        for (int k = 0; k < 8; ++k) {
            float v = bf2f(h1u.u[k]) * scv[k] + shv[k];
            v = v > 0.f ? v : (__expf(v) - 1.f);
            o.u[k] = f2bf(fmaxf(v, a[k] * inv + bb[k]));
        }
    }
    *(int4*)(&jkS[nloc * 264 + l * 8]) = o.v;
    __syncthreads();
    // GEMM phase: 16x256 @ 256x64 on waves 0..3 (N-tile = wave), 8 MFMAs each
    if (wave < 4) {
        int quad = lane >> 4, l16 = lane & 15;
        f32x4 acc = (f32x4){0.f, 0.f, 0.f, 0.f};
#pragma unroll
        for (int kc = 0; kc < HC; kc += 32) {
            bf16x8 af = *(const bf16x8*)(&jkS[l16 * 264 + kc + quad * 8]);
            bf16x8 bfr = *(const bf16x8*)(&BsF[(wave * 16 + l16) * 264 + kc + quad * 8]);
            acc = __builtin_amdgcn_mfma_f32_16x16x32_bf16(af, bfr, acc, 0, 0, 0);
        }
        int row0 = blockIdx.x * 16 + quad * 4;
        int c = wave * 16 + l16;
        float bc = linb[c];
#pragma unroll
        for (int r = 0; r < 4; ++r)
            out[(size_t)(row0 + r) * NOUT + c] = acc[r] + bc;
    }
}

// ---------------- batch norm stats + fused last-block finalize -------------
// 200 blocks: ~102K global atomics total (100-way contention) — proven cheap.
__global__ __launch_bounds__(256) void bn_stats_kernel(const unsigned short* __restrict__ x,
                                                       float* __restrict__ acc,
                                                       const float* __restrict__ gamma,
                                                       const float* __restrict__ beta,
                                                       float* __restrict__ sc,
                                                       int* __restrict__ ticket) {
    int c = threadIdx.x;
    int r0 = blockIdx.x * 200;
    float s = 0.f, s2 = 0.f;
    for (int r = r0; r < r0 + 200; ++r) {
        float v = bf2f(x[(size_t)r * HC + c]);
        s += v; s2 += v * v;
    }
    atomicAdd(&acc[c], s);
    atomicAdd(&acc[HC + c], s2);
    __threadfence();
    __syncthreads();
    __shared__ int is_last;
    if (c == 0) is_last = (atomicAdd(ticket, 1) == (int)gridDim.x - 1);
    __syncthreads();
    if (is_last) {
        float sum = atomicAdd(&acc[c], 0.f);   // coherent readback
        float sq  = atomicAdd(&acc[HC + c], 0.f);
        float mean = sum * (1.f / N_NODES);
        float var = sq * (1.f / N_NODES) - mean * mean;
        float inv = rsqrtf(var + 1e-5f);
        float scale = gamma[c] * inv;
        sc[c] = scale;
        sc[HC + c] = beta[c] - mean * scale;
    }
}

extern "C" void kernel_launch(void* const* d_in, const int* in_sizes, int n_in,
                              void* d_out, int out_size, void* d_ws, size_t ws_size,
                              hipStream_t stream) {
    const float* x      = (const float*)d_in[0];
    const int*   ei     = (const int*)d_in[1];
    const float* W1     = (const float*)d_in[2];
    const float* a1_src = (const float*)d_in[3];
    const float* a1_dst = (const float*)d_in[4];
    const float* b1     = (const float*)d_in[5];
    const float* bn_g   = (const float*)d_in[6];
    const float* bn_b   = (const float*)d_in[7];
    const float* W2     = (const float*)d_in[8];
    const float* a2_src = (const float*)d_in[9];
    const float* a2_dst = (const float*)d_in[10];
    const float* b2     = (const float*)d_in[11];
    const float* linW   = (const float*)d_in[12];
    const float* linb   = (const float*)d_in[13];
    float* out = (float*)d_out;

    char* ws = (char*)d_ws;
    const size_t NHC_BF = (size_t)N_NODES * HC * 2;   // 20.48 MB
    unsigned short* hpre_b  = (unsigned short*)(ws);                  // h_pre (both layers)
    unsigned short* h1agg_b = (unsigned short*)(ws + NHC_BF);         // agg1 (pre-BN)
    // slots at 2*,3* NHC_BF previously held h1p / jk; now unused (fused away)
    char* p = ws + 4 * NHC_BF;
    unsigned short* W1t   = (unsigned short*)p; p += (size_t)F_IN * HC * 2;
    unsigned short* W2t   = (unsigned short*)p; p += (size_t)HC * HC * 2;
    unsigned short* linWt = (unsigned short*)p; p += (size_t)HC * NOUT * 2;
    float* e_src   = (float*)p;  p += (size_t)N_NODES * NHEAD * 4;
    float* e_dst   = (float*)p;  p += (size_t)N_NODES * NHEAD * 4;
    // zero region: cursor + ticket (40004 ints)
    int*   cursor  = (int*)p;    p += (size_t)N_NODES * 4;
    int*   ticket  = (int*)p;    p += 4 * 4;
    int*   esorted = (int*)p;    p += (size_t)N_NODES * SLOTCAP * 4;  // 6.4 MB
    float* bnacc   = (float*)p;  p += 2 * HC * 4;
    float* bnsc    = (float*)p;  p += 2 * HC * 4;

    // 1. prep: weight converts + zero cursor/ticket/bnacc
    prep_kernel<<<489, 256, 0, stream>>>(W1, W2, linW, W1t, W2t, linWt, cursor, bnacc);

    // 2. layer-1 wide GEMM (f32 A) + fused scores + fused CSR scatter
    gemm_wide<1, 1><<<N_NODES / 64 + (N_EDGES + 255) / 256, 256, 0, stream>>>(
        x, W1t, nullptr, hpre_b, a1_src, a1_dst, e_src, e_dst, F_IN,
        ei, cursor, esorted);

    // 3. aggregate 1
    aggregate_kernel<<<N_NODES / 8, 256, 0, stream>>>(
        hpre_b, e_src, e_dst, cursor, esorted, b1, h1agg_b);

    // 4. BN stats + finalize (ticket-fused, 200 blocks)
    bn_stats_kernel<<<N_NODES / 200, 256, 0, stream>>>(h1agg_b, bnacc, bn_g, bn_b,
                                                       bnsc, ticket);

    // 5. layer-2 wide GEMM (BN+ELU fused into staging) + scores
    gemm_wide<3, 0><<<N_NODES / 64, 256, 0, stream>>>(
        h1agg_b, W2t, bnsc, hpre_b, a2_src, a2_dst, e_src, e_dst, HC,
        nullptr, nullptr, nullptr);

    // 6. aggregate 2 + JK max (BN+ELU recompute) + fused final projection
    aggregate2_fused<<<N_NODES / 16, 512, 0, stream>>>(
        hpre_b, e_src, e_dst, cursor, esorted, b2, h1agg_b, bnsc, linWt, linb, out);
}

// Round 3
// 221.453 us; speedup vs baseline: 1.0430x; 1.0430x over previous
//
#include <hip/hip_runtime.h>
#include <math.h>

#define N_NODES 40000
#define N_EDGES 320000
#define F_IN 128
#define NHEAD 4
#define HC 256
#define NOUT 64
#define SLOTCAP 40   // max degree capacity; P(Poisson(8) >= 40) ~ 1e-18 per node
#define BN_RBLK 40   // bn_reduce grid

typedef __attribute__((ext_vector_type(8))) __bf16 bf16x8;
typedef __attribute__((ext_vector_type(4))) float f32x4;

static __device__ __forceinline__ unsigned short f2bf(float f) {
    union { float f; unsigned u; } v; v.f = f;
    unsigned r = v.u + 0x7FFFu + ((v.u >> 16) & 1u);
    return (unsigned short)(r >> 16);
}
static __device__ __forceinline__ float bf2f(unsigned short s) {
    union { unsigned u; float f; } v; v.u = ((unsigned)s) << 16;
    return v.f;
}

// ---------------- prep: weight converts + zero cursor/ticket/bnacc --------
__global__ __launch_bounds__(256) void prep_kernel(const float* __restrict__ W1,
                                                   const float* __restrict__ W2,
                                                   const float* __restrict__ linW,
                                                   unsigned short* __restrict__ W1t,
                                                   unsigned short* __restrict__ W2t,
                                                   unsigned short* __restrict__ linWt,
                                                   int* __restrict__ zero_ints,
                                                   float* __restrict__ bnacc) {
    int b = blockIdx.x, tid = threadIdx.x;
    if (b < 128) {
        int t = b * 256 + tid;
        int k = t >> 8, n = t & 255;
        W1t[n * 128 + k] = f2bf(W1[t]);
    } else if (b < 384) {
        int t = (b - 128) * 256 + tid;
        int k = t >> 8, n = t & 255;
        W2t[n * 256 + k] = f2bf(W2[t]);
    } else if (b < 448) {
        int t = (b - 384) * 256 + tid;
        int k = t >> 6, n = t & 63;
        linWt[n * 256 + k] = f2bf(linW[t]);
    } else if (b < 488) {
        int i = (b - 448) * 1024 + tid * 4;
        if (i < 40004) *(int4*)(zero_ints + i) = make_int4(0, 0, 0, 0);
    } else {
        if (tid < 512) bnacc[tid] = 0.f;
    }
}

// ---------------- wide MFMA GEMM: 64 rows x 256 cols, dbuf LDS ------------
// AMODE 1: A = f32[M,K] (convert in staging)
// AMODE 3: A = bf16[M,K], elu(x*sc+shift) in staging (via __expf)
// SCATTER 1: blocks >= 625 instead do direct-slot CSR scatter
// LDS double-buffered: ONE barrier per K-step.
template <int AMODE, int SCATTER>
__global__ __launch_bounds__(256) void gemm_wide(const void* __restrict__ Aptr,
                                                 const unsigned short* __restrict__ Bt,
                                                 const float* __restrict__ sc,
                                                 unsigned short* __restrict__ Cb,
                                                 const float* __restrict__ asrc,
                                                 const float* __restrict__ adst,
                                                 float* __restrict__ es,
                                                 float* __restrict__ ed,
                                                 int K,
                                                 const int* __restrict__ ei,
                                                 int* __restrict__ cursor,
                                                 int* __restrict__ esorted) {
    __shared__ unsigned short As[2][64 * 32];
    __shared__ unsigned short Bs[2][256 * 32];
    int tid = threadIdx.x;
    if (SCATTER && blockIdx.x >= N_NODES / 64) {
        int e = (blockIdx.x - N_NODES / 64) * 256 + tid;
        if (e < N_EDGES) {
            int d = ei[N_EDGES + e];
            int s = ei[e];
            int pos = atomicAdd(&cursor[d], 1);
            esorted[d * SLOTCAP + pos] = s;
        }
        return;
    }
    int row0 = blockIdx.x * 64;
    int w = tid >> 6, lane = tid & 63;
    int quad = lane >> 4, l16 = lane & 15;
    f32x4 acc[4][4];
#pragma unroll
    for (int mi = 0; mi < 4; ++mi)
#pragma unroll
        for (int ni = 0; ni < 4; ++ni) acc[mi][ni] = (f32x4){0.f, 0.f, 0.f, 0.f};

    int srow = tid >> 2, schunk = (tid & 3) * 8;
    int brow = tid >> 1, bchunk = (tid & 1) * 16;

    float4 pa0, pa1;
    int4 pai;
    int4 pb[4];
    if (AMODE == 1) {
        const float* Af = (const float*)Aptr;
        size_t base = (size_t)(row0 + srow) * K + schunk;
        pa0 = *(const float4*)(Af + base);
        pa1 = *(const float4*)(Af + base + 4);
    } else {
        pai = *(const int4*)((const unsigned short*)Aptr + (size_t)(row0 + srow) * K + schunk);
    }
    {
        const unsigned short* s0 = Bt + (size_t)brow * K + bchunk;
        const unsigned short* s1 = Bt + (size_t)(128 + brow) * K + bchunk;
        pb[0] = *(const int4*)s0; pb[1] = *(const int4*)(s0 + 8);
        pb[2] = *(const int4*)s1; pb[3] = *(const int4*)(s1 + 8);
    }

    for (int kc = 0; kc < K; kc += 32) {
        int buf = (kc >> 5) & 1;
        union { int4 v; unsigned short u[8]; } aS;
        if (AMODE == 1) {
            aS.u[0] = f2bf(pa0.x); aS.u[1] = f2bf(pa0.y);
            aS.u[2] = f2bf(pa0.z); aS.u[3] = f2bf(pa0.w);
            aS.u[4] = f2bf(pa1.x); aS.u[5] = f2bf(pa1.y);
            aS.u[6] = f2bf(pa1.z); aS.u[7] = f2bf(pa1.w);
        } else {
            union { int4 v; unsigned short u[8]; } a;
            a.v = pai;
#pragma unroll
            for (int j = 0; j < 8; ++j) {
                int c = kc + schunk + j;
                float v = bf2f(a.u[j]) * sc[c] + sc[HC + c];
                v = v > 0.f ? v : (__expf(v) - 1.f);
                aS.u[j] = f2bf(v);
            }
        }
        int4 bS0 = pb[0], bS1 = pb[1], bS2 = pb[2], bS3 = pb[3];
        int kn = kc + 32;
        if (kn < K) {
            if (AMODE == 1) {
                const float* Af = (const float*)Aptr;
                size_t base = (size_t)(row0 + srow) * K + kn + schunk;
                pa0 = *(const float4*)(Af + base);
                pa1 = *(const float4*)(Af + base + 4);
            } else {
                pai = *(const int4*)((const unsigned short*)Aptr +
                                     (size_t)(row0 + srow) * K + kn + schunk);
            }
            const unsigned short* s0 = Bt + (size_t)brow * K + kn + bchunk;
            const unsigned short* s1 = Bt + (size_t)(128 + brow) * K + kn + bchunk;
            pb[0] = *(const int4*)s0; pb[1] = *(const int4*)(s0 + 8);
            pb[2] = *(const int4*)s1; pb[3] = *(const int4*)(s1 + 8);
        }
        *(int4*)(&As[buf][srow * 32 + schunk]) = aS.v;
        *(int4*)(&Bs[buf][brow * 32 + bchunk]) = bS0;
        *(int4*)(&Bs[buf][brow * 32 + bchunk + 8]) = bS1;
        *(int4*)(&Bs[buf][(128 + brow) * 32 + bchunk]) = bS2;
        *(int4*)(&Bs[buf][(128 + brow) * 32 + bchunk + 8]) = bS3;
        __syncthreads();
        bf16x8 af[4], bfr[4];
#pragma unroll
        for (int mi = 0; mi < 4; ++mi)
            af[mi] = *(const bf16x8*)(&As[buf][(mi * 16 + l16) * 32 + quad * 8]);
#pragma unroll
        for (int ni = 0; ni < 4; ++ni)
            bfr[ni] = *(const bf16x8*)(&Bs[buf][(w * 64 + ni * 16 + l16) * 32 + quad * 8]);
#pragma unroll
        for (int mi = 0; mi < 4; ++mi)
#pragma unroll
            for (int ni = 0; ni < 4; ++ni)
                acc[mi][ni] = __builtin_amdgcn_mfma_f32_16x16x32_bf16(
                    af[mi], bfr[ni], acc[mi][ni], 0, 0, 0);
        // no trailing barrier: next iteration writes the other LDS buffer
    }
#pragma unroll
    for (int mi = 0; mi < 4; ++mi)
#pragma unroll
        for (int ni = 0; ni < 4; ++ni) {
            int r0 = row0 + mi * 16 + quad * 4;
            int c = w * 64 + ni * 16 + l16;
#pragma unroll
            for (int r = 0; r < 4; ++r)
                Cb[(size_t)(r0 + r) * HC + c] = f2bf(acc[mi][ni][r]);
        }
    // fused attention scores (head = w), wave-local
    float as_v[4], ad_v[4];
#pragma unroll
    for (int ni = 0; ni < 4; ++ni) {
        int cl = ni * 16 + l16;
        as_v[ni] = asrc[w * 64 + cl];
        ad_v[ni] = adst[w * 64 + cl];
    }
#pragma unroll
    for (int mi = 0; mi < 4; ++mi)
#pragma unroll
        for (int r = 0; r < 4; ++r) {
            float s = 0.f, d = 0.f;
#pragma unroll
            for (int ni = 0; ni < 4; ++ni) {
                s += acc[mi][ni][r] * as_v[ni];
                d += acc[mi][ni][r] * ad_v[ni];
            }
#pragma unroll
            for (int off = 1; off < 16; off <<= 1) {
                s += __shfl_xor(s, off);
                d += __shfl_xor(d, off);
            }
            if (l16 == 0) {
                int row = row0 + mi * 16 + quad * 4 + r;
                es[(size_t)row * NHEAD + w] = s;
                ed[(size_t)row * NHEAD + w] = d;
            }
        }
}

// ------- softmax + aggregation (layer 1) + BN partial stats ---------------
// 2 nodes/wave, bf16 gather (16B/lane). BN stats are computed HERE from the
// pre-rounding f32 outputs via an 8KB LDS transpose + ONE non-atomic 2KB
// partial write per block ([5000][512] f32). This replaces bn_stats's
// 20.5MB strided-u16 re-read. (R10/R11 showed atomic-fused stats are
// catastrophic; per-block non-atomic partials avoid that entirely.)
__global__ __launch_bounds__(256) void aggregate_kernel(const unsigned short* __restrict__ h,
                                                        const float* __restrict__ es,
                                                        const float* __restrict__ ed,
                                                        const int* __restrict__ deg,
                                                        const int* __restrict__ esorted,
                                                        const float* __restrict__ bias,
                                                        unsigned short* __restrict__ outb,
                                                        float* __restrict__ partials) {
    __shared__ float sdata[8][256];
    int tid = threadIdx.x;
    int wave = tid >> 6, lane = tid & 63;
    int half = lane >> 5, l = lane & 31;       // 2 nodes per wave, 32 lanes each
    int nloc = wave * 2 + half;
    int node = blockIdx.x * 8 + nloc;
    int hh = l >> 3;                            // 8 channels/lane -> head = l>>3
    float edv = ed[node * NHEAD + hh];
    int d = deg[node];
    int beg = node * SLOTCAP;
    float dsum = 0.f;
    float a[8] = {0.f, 0.f, 0.f, 0.f, 0.f, 0.f, 0.f, 0.f};
    for (int i = 0; i < d; i += 8) {
        int s[8];
        int4 hv[8];
        float ep[8];
#pragma unroll
        for (int j = 0; j < 8; ++j) {
            int slot = i + j;
            s[j] = esorted[beg + (slot < d ? slot : d - 1)];
        }
#pragma unroll
        for (int j = 0; j < 8; ++j)
            hv[j] = *(const int4*)(h + (size_t)s[j] * HC + l * 8);
#pragma unroll
        for (int j = 0; j < 8; ++j)
            ep[j] = es[s[j] * NHEAD + hh];
#pragma unroll
        for (int j = 0; j < 8; ++j) {
            float e = ep[j] + edv;
            e = e > 0.f ? e : 0.2f * e;
            float w = __expf(e);
            w = (i + j < d) ? w : 0.f;   // adding exact 0.0f: order-identical sums
            dsum += w;
            union { int4 v; unsigned short u[8]; } hu;
            hu.v = hv[j];
#pragma unroll
            for (int k = 0; k < 8; ++k) a[k] += w * bf2f(hu.u[k]);
        }
    }
    float inv = 1.f / (dsum + 1e-16f);
    float4 bv0 = *(const float4*)(bias + l * 8);
    float4 bv1 = *(const float4*)(bias + l * 8 + 4);
    float bb[8] = {bv0.x, bv0.y, bv0.z, bv0.w, bv1.x, bv1.y, bv1.z, bv1.w};
    float ov[8];
    union { int4 v; unsigned short u[8]; } o;
#pragma unroll
    for (int k = 0; k < 8; ++k) {
        ov[k] = a[k] * inv + bb[k];
        o.u[k] = f2bf(ov[k]);
    }
    *(int4*)(outb + (size_t)node * HC + l * 8) = o.v;
    // BN partial stats: transpose via LDS, 256 threads sum 8 nodes each
#pragma unroll
    for (int k = 0; k < 8; ++k) sdata[nloc][l * 8 + k] = ov[k];
    __syncthreads();
    {
        int c = tid;
        float s = 0.f, s2 = 0.f;
#pragma unroll
        for (int n = 0; n < 8; ++n) {
            float v = sdata[n][c];
            s += v; s2 += v * v;
        }
        float* pb = partials + (size_t)blockIdx.x * 512;
        pb[c] = s;
        pb[256 + c] = s2;
    }
}

// ------- layer-2 aggregation + JK max (BN+ELU recompute) + projection ------
__global__ __launch_bounds__(512) void aggregate2_fused(const unsigned short* __restrict__ h,
                                                        const float* __restrict__ es,
                                                        const float* __restrict__ ed,
                                                        const int* __restrict__ deg,
                                                        const int* __restrict__ esorted,
                                                        const float* __restrict__ bias,
                                                        const unsigned short* __restrict__ h1agg,
                                                        const float* __restrict__ bnsc,
                                                        const unsigned short* __restrict__ linWt,
                                                        const float* __restrict__ linb,
                                                        float* __restrict__ out) {
    __shared__ unsigned short jkS[16 * 264];
    __shared__ unsigned short BsF[64 * 264];
    int tid = threadIdx.x;
    // stage linWt [64][256] -> BsF (512 threads x 32 shorts), overlaps agg
    {
        int n = tid >> 3, k0 = (tid & 7) * 32;
        const int4* src = (const int4*)(linWt + n * 256 + k0);
        int4 v0 = src[0], v1 = src[1], v2 = src[2], v3 = src[3];
        int4* dstp = (int4*)(&BsF[n * 264 + k0]);
        dstp[0] = v0; dstp[1] = v1; dstp[2] = v2; dstp[3] = v3;
    }
    int wave = tid >> 6, lane = tid & 63;
    int half = lane >> 5, l = lane & 31;       // 2 nodes per wave, 32 lanes each
    int nloc = wave * 2 + half;                // 0..15
    int node = blockIdx.x * 16 + nloc;
    int hh = l >> 3;
    float edv = ed[node * NHEAD + hh];
    int d = deg[node];
    int beg = node * SLOTCAP;
    float dsum = 0.f;
    float a[8] = {0.f, 0.f, 0.f, 0.f, 0.f, 0.f, 0.f, 0.f};
    for (int i = 0; i < d; i += 8) {
        int s[8];
        int4 hv[8];
        float ep[8];
#pragma unroll
        for (int j = 0; j < 8; ++j) {
            int slot = i + j;
            s[j] = esorted[beg + (slot < d ? slot : d - 1)];
        }
#pragma unroll
        for (int j = 0; j < 8; ++j)
            hv[j] = *(const int4*)(h + (size_t)s[j] * HC + l * 8);
#pragma unroll
        for (int j = 0; j < 8; ++j)
            ep[j] = es[s[j] * NHEAD + hh];
#pragma unroll
        for (int j = 0; j < 8; ++j) {
            float e = ep[j] + edv;
            e = e > 0.f ? e : 0.2f * e;
            float w = __expf(e);
            w = (i + j < d) ? w : 0.f;
            dsum += w;
            union { int4 v; unsigned short u[8]; } hu;
            hu.v = hv[j];
#pragma unroll
            for (int k = 0; k < 8; ++k) a[k] += w * bf2f(hu.u[k]);
        }
    }
    float inv = 1.f / (dsum + 1e-16f);
    float4 bv0 = *(const float4*)(bias + l * 8);
    float4 bv1 = *(const float4*)(bias + l * 8 + 4);
    float bb[8] = {bv0.x, bv0.y, bv0.z, bv0.w, bv1.x, bv1.y, bv1.z, bv1.w};
    union { int4 v; unsigned short u[8]; } o;
    {
        union { int4 v; unsigned short u[8]; } h1u;
        h1u.v = *(const int4*)(h1agg + (size_t)node * HC + l * 8);
        float4 s0 = *(const float4*)(bnsc + l * 8);
        float4 s1 = *(const float4*)(bnsc + l * 8 + 4);
        float4 t0 = *(const float4*)(bnsc + HC + l * 8);
        float4 t1 = *(const float4*)(bnsc + HC + l * 8 + 4);
        float scv[8] = {s0.x, s0.y, s0.z, s0.w, s1.x, s1.y, s1.z, s1.w};
        float shv[8] = {t0.x, t0.y, t0.z, t0.w, t1.x, t1.y, t1.z, t1.w};
#pragma unroll
        for (int k = 0; k < 8; ++k) {
            float v = bf2f(h1u.u[k]) * scv[k] + shv[k];
            v = v > 0.f ? v : (__expf(v) - 1.f);
            o.u[k] = f2bf(fmaxf(v, a[k] * inv + bb[k]));
        }
    }
    *(int4*)(&jkS[nloc * 264 + l * 8]) = o.v;
    __syncthreads();
    // GEMM phase: 16x256 @ 256x64 on waves 0..3 (N-tile = wave), 8 MFMAs each
    if (wave < 4) {
        int quad = lane >> 4, l16 = lane & 15;
        f32x4 acc = (f32x4){0.f, 0.f, 0.f, 0.f};
#pragma unroll
        for (int kc = 0; kc < HC; kc += 32) {
            bf16x8 af = *(const bf16x8*)(&jkS[l16 * 264 + kc + quad * 8]);
            bf16x8 bfr = *(const bf16x8*)(&BsF[(wave * 16 + l16) * 264 + kc + quad * 8]);
            acc = __builtin_amdgcn_mfma_f32_16x16x32_bf16(af, bfr, acc, 0, 0, 0);
        }
        int row0 = blockIdx.x * 16 + quad * 4;
        int c = wave * 16 + l16;
        float bc = linb[c];
#pragma unroll
        for (int r = 0; r < 4; ++r)
            out[(size_t)(row0 + r) * NOUT + c] = acc[r] + bc;
    }
}

// ---------------- BN: reduce per-block partials + ticket finalize ----------
// 40 blocks, coalesced f32 reads (10.2MB), 20K atomics @ 40-way contention.
__global__ __launch_bounds__(256) void bn_reduce_kernel(const float* __restrict__ partials,
                                                        float* __restrict__ acc,
                                                        const float* __restrict__ gamma,
                                                        const float* __restrict__ beta,
                                                        float* __restrict__ sc,
                                                        int* __restrict__ ticket) {
    int t = threadIdx.x;
    const int per = (N_NODES / 8) / BN_RBLK;   // 125
    int b0 = blockIdx.x * per;
    float A = 0.f, B = 0.f;
    for (int b = b0; b < b0 + per; ++b) {
        A += partials[(size_t)b * 512 + t];
        B += partials[(size_t)b * 512 + 256 + t];
    }
    atomicAdd(&acc[t], A);
    atomicAdd(&acc[HC + t], B);
    __threadfence();
    __syncthreads();
    __shared__ int is_last;
    if (t == 0) is_last = (atomicAdd(ticket, 1) == BN_RBLK - 1);
    __syncthreads();
    if (is_last) {
        float sum = atomicAdd(&acc[t], 0.f);   // coherent readback
        float sq  = atomicAdd(&acc[HC + t], 0.f);
        float mean = sum * (1.f / N_NODES);
        float var = sq * (1.f / N_NODES) - mean * mean;
        float inv = rsqrtf(var + 1e-5f);
        float scale = gamma[t] * inv;
        sc[t] = scale;
        sc[HC + t] = beta[t] - mean * scale;
    }
}

extern "C" void kernel_launch(void* const* d_in, const int* in_sizes, int n_in,
                              void* d_out, int out_size, void* d_ws, size_t ws_size,
                              hipStream_t stream) {
    const float* x      = (const float*)d_in[0];
    const int*   ei     = (const int*)d_in[1];
    const float* W1     = (const float*)d_in[2];
    const float* a1_src = (const float*)d_in[3];
    const float* a1_dst = (const float*)d_in[4];
    const float* b1     = (const float*)d_in[5];
    const float* bn_g   = (const float*)d_in[6];
    const float* bn_b   = (const float*)d_in[7];
    const float* W2     = (const float*)d_in[8];
    const float* a2_src = (const float*)d_in[9];
    const float* a2_dst = (const float*)d_in[10];
    const float* b2     = (const float*)d_in[11];
    const float* linW   = (const float*)d_in[12];
    const float* linb   = (const float*)d_in[13];
    float* out = (float*)d_out;

    char* ws = (char*)d_ws;
    const size_t NHC_BF = (size_t)N_NODES * HC * 2;   // 20.48 MB
    unsigned short* hpre_b  = (unsigned short*)(ws);                  // h_pre (both layers)
    unsigned short* h1agg_b = (unsigned short*)(ws + NHC_BF);         // agg1 (pre-BN)
    float* partials = (float*)(ws + 2 * NHC_BF);                      // [5000][512] f32
    char* p = ws + 4 * NHC_BF;
    unsigned short* W1t   = (unsigned short*)p; p += (size_t)F_IN * HC * 2;
    unsigned short* W2t   = (unsigned short*)p; p += (size_t)HC * HC * 2;
    unsigned short* linWt = (unsigned short*)p; p += (size_t)HC * NOUT * 2;
    float* e_src   = (float*)p;  p += (size_t)N_NODES * NHEAD * 4;
    float* e_dst   = (float*)p;  p += (size_t)N_NODES * NHEAD * 4;
    // zero region: cursor + ticket (40004 ints)
    int*   cursor  = (int*)p;    p += (size_t)N_NODES * 4;
    int*   ticket  = (int*)p;    p += 4 * 4;
    int*   esorted = (int*)p;    p += (size_t)N_NODES * SLOTCAP * 4;  // 6.4 MB
    float* bnacc   = (float*)p;  p += 2 * HC * 4;
    float* bnsc    = (float*)p;  p += 2 * HC * 4;

    // 1. prep: weight converts + zero cursor/ticket/bnacc
    prep_kernel<<<489, 256, 0, stream>>>(W1, W2, linW, W1t, W2t, linWt, cursor, bnacc);

    // 2. layer-1 wide GEMM (f32 A) + fused scores + fused CSR scatter
    gemm_wide<1, 1><<<N_NODES / 64 + (N_EDGES + 255) / 256, 256, 0, stream>>>(
        x, W1t, nullptr, hpre_b, a1_src, a1_dst, e_src, e_dst, F_IN,
        ei, cursor, esorted);

    // 3. aggregate 1 (+ BN partial stats from pre-rounding f32)
    aggregate_kernel<<<N_NODES / 8, 256, 0, stream>>>(
        hpre_b, e_src, e_dst, cursor, esorted, b1, h1agg_b, partials);

    // 4. BN partial reduce + finalize (ticket-fused, 40 blocks)
    bn_reduce_kernel<<<BN_RBLK, 256, 0, stream>>>(partials, bnacc, bn_g, bn_b,
                                                  bnsc, ticket);

    // 5. layer-2 wide GEMM (BN+ELU fused into staging) + scores
    gemm_wide<3, 0><<<N_NODES / 64, 256, 0, stream>>>(
        h1agg_b, W2t, bnsc, hpre_b, a2_src, a2_dst, e_src, e_dst, HC,
        nullptr, nullptr, nullptr);

    // 6. aggregate 2 + JK max (BN+ELU recompute) + fused final projection
    aggregate2_fused<<<N_NODES / 16, 512, 0, stream>>>(
        hpre_b, e_src, e_dst, cursor, esorted, b2, h1agg_b, bnsc, linWt, linb, out);
}

// Round 5
// 220.419 us; speedup vs baseline: 1.0479x; 1.0047x over previous
//
#include <hip/hip_runtime.h>
#include <math.h>

#define N_NODES 40000
#define N_EDGES 320000
#define F_IN 128
#define NHEAD 4
#define HC 256
#define NOUT 64
#define SLOTCAP 40   // max degree capacity; P(Poisson(8) >= 40) ~ 1e-18 per node
#define BN_RBLK 40   // bn_reduce grid

typedef __attribute__((ext_vector_type(8))) __bf16 bf16x8;
typedef __attribute__((ext_vector_type(4))) float f32x4;

static __device__ __forceinline__ unsigned short f2bf(float f) {
    union { float f; unsigned u; } v; v.f = f;
    unsigned r = v.u + 0x7FFFu + ((v.u >> 16) & 1u);
    return (unsigned short)(r >> 16);
}
static __device__ __forceinline__ float bf2f(unsigned short s) {
    union { unsigned u; float f; } v; v.u = ((unsigned)s) << 16;
    return v.f;
}

// ---------------- prep: weight converts + zero cursor/ticket/bnacc --------
__global__ __launch_bounds__(256) void prep_kernel(const float* __restrict__ W1,
                                                   const float* __restrict__ W2,
                                                   const float* __restrict__ linW,
                                                   unsigned short* __restrict__ W1t,
                                                   unsigned short* __restrict__ W2t,
                                                   unsigned short* __restrict__ linWt,
                                                   int* __restrict__ zero_ints,
                                                   float* __restrict__ bnacc) {
    int b = blockIdx.x, tid = threadIdx.x;
    if (b < 128) {
        int t = b * 256 + tid;
        int k = t >> 8, n = t & 255;
        W1t[n * 128 + k] = f2bf(W1[t]);
    } else if (b < 384) {
        int t = (b - 128) * 256 + tid;
        int k = t >> 8, n = t & 255;
        W2t[n * 256 + k] = f2bf(W2[t]);
    } else if (b < 448) {
        int t = (b - 384) * 256 + tid;
        int k = t >> 6, n = t & 63;
        linWt[n * 256 + k] = f2bf(linW[t]);
    } else if (b < 488) {
        int i = (b - 448) * 1024 + tid * 4;
        if (i < 40004) *(int4*)(zero_ints + i) = make_int4(0, 0, 0, 0);
    } else {
        if (tid < 512) bnacc[tid] = 0.f;
    }
}

// ---------------- wide MFMA GEMM: 64 rows x 256 cols, dbuf LDS ------------
// AMODE 1: A = f32[M,K] (convert in staging)
// AMODE 3: A = bf16[M,K], elu(x*sc+shift) in staging (via __expf)
// SCATTER 1: blocks >= 625 instead do direct-slot CSR scatter (u16 payload)
// LDS double-buffered: ONE barrier per K-step.
template <int AMODE, int SCATTER>
__global__ __launch_bounds__(256) void gemm_wide(const void* __restrict__ Aptr,
                                                 const unsigned short* __restrict__ Bt,
                                                 const float* __restrict__ sc,
                                                 unsigned short* __restrict__ Cb,
                                                 const float* __restrict__ asrc,
                                                 const float* __restrict__ adst,
                                                 float* __restrict__ es,
                                                 float* __restrict__ ed,
                                                 int K,
                                                 const int* __restrict__ ei,
                                                 int* __restrict__ cursor,
                                                 unsigned short* __restrict__ esorted) {
    __shared__ unsigned short As[2][64 * 32];
    __shared__ unsigned short Bs[2][256 * 32];
    int tid = threadIdx.x;
    if (SCATTER && blockIdx.x >= N_NODES / 64) {
        int e = (blockIdx.x - N_NODES / 64) * 256 + tid;
        if (e < N_EDGES) {
            int d = ei[N_EDGES + e];
            int s = ei[e];
            int pos = atomicAdd(&cursor[d], 1);
            esorted[d * SLOTCAP + pos] = (unsigned short)s;
        }
        return;
    }
    int row0 = blockIdx.x * 64;
    int w = tid >> 6, lane = tid & 63;
    int quad = lane >> 4, l16 = lane & 15;
    f32x4 acc[4][4];
#pragma unroll
    for (int mi = 0; mi < 4; ++mi)
#pragma unroll
        for (int ni = 0; ni < 4; ++ni) acc[mi][ni] = (f32x4){0.f, 0.f, 0.f, 0.f};

    int srow = tid >> 2, schunk = (tid & 3) * 8;
    int brow = tid >> 1, bchunk = (tid & 1) * 16;

    float4 pa0, pa1;
    int4 pai;
    int4 pb[4];
    if (AMODE == 1) {
        const float* Af = (const float*)Aptr;
        size_t base = (size_t)(row0 + srow) * K + schunk;
        pa0 = *(const float4*)(Af + base);
        pa1 = *(const float4*)(Af + base + 4);
    } else {
        pai = *(const int4*)((const unsigned short*)Aptr + (size_t)(row0 + srow) * K + schunk);
    }
    {
        const unsigned short* s0 = Bt + (size_t)brow * K + bchunk;
        const unsigned short* s1 = Bt + (size_t)(128 + brow) * K + bchunk;
        pb[0] = *(const int4*)s0; pb[1] = *(const int4*)(s0 + 8);
        pb[2] = *(const int4*)s1; pb[3] = *(const int4*)(s1 + 8);
    }

    for (int kc = 0; kc < K; kc += 32) {
        int buf = (kc >> 5) & 1;
        union { int4 v; unsigned short u[8]; } aS;
        if (AMODE == 1) {
            aS.u[0] = f2bf(pa0.x); aS.u[1] = f2bf(pa0.y);
            aS.u[2] = f2bf(pa0.z); aS.u[3] = f2bf(pa0.w);
            aS.u[4] = f2bf(pa1.x); aS.u[5] = f2bf(pa1.y);
            aS.u[6] = f2bf(pa1.z); aS.u[7] = f2bf(pa1.w);
        } else {
            union { int4 v; unsigned short u[8]; } a;
            a.v = pai;
#pragma unroll
            for (int j = 0; j < 8; ++j) {
                int c = kc + schunk + j;
                float v = bf2f(a.u[j]) * sc[c] + sc[HC + c];
                v = v > 0.f ? v : (__expf(v) - 1.f);
                aS.u[j] = f2bf(v);
            }
        }
        int4 bS0 = pb[0], bS1 = pb[1], bS2 = pb[2], bS3 = pb[3];
        int kn = kc + 32;
        if (kn < K) {
            if (AMODE == 1) {
                const float* Af = (const float*)Aptr;
                size_t base = (size_t)(row0 + srow) * K + kn + schunk;
                pa0 = *(const float4*)(Af + base);
                pa1 = *(const float4*)(Af + base + 4);
            } else {
                pai = *(const int4*)((const unsigned short*)Aptr +
                                     (size_t)(row0 + srow) * K + kn + schunk);
            }
            const unsigned short* s0 = Bt + (size_t)brow * K + kn + bchunk;
            const unsigned short* s1 = Bt + (size_t)(128 + brow) * K + kn + bchunk;
            pb[0] = *(const int4*)s0; pb[1] = *(const int4*)(s0 + 8);
            pb[2] = *(const int4*)s1; pb[3] = *(const int4*)(s1 + 8);
        }
        *(int4*)(&As[buf][srow * 32 + schunk]) = aS.v;
        *(int4*)(&Bs[buf][brow * 32 + bchunk]) = bS0;
        *(int4*)(&Bs[buf][brow * 32 + bchunk + 8]) = bS1;
        *(int4*)(&Bs[buf][(128 + brow) * 32 + bchunk]) = bS2;
        *(int4*)(&Bs[buf][(128 + brow) * 32 + bchunk + 8]) = bS3;
        __syncthreads();
        bf16x8 af[4], bfr[4];
#pragma unroll
        for (int mi = 0; mi < 4; ++mi)
            af[mi] = *(const bf16x8*)(&As[buf][(mi * 16 + l16) * 32 + quad * 8]);
#pragma unroll
        for (int ni = 0; ni < 4; ++ni)
            bfr[ni] = *(const bf16x8*)(&Bs[buf][(w * 64 + ni * 16 + l16) * 32 + quad * 8]);
#pragma unroll
        for (int mi = 0; mi < 4; ++mi)
#pragma unroll
            for (int ni = 0; ni < 4; ++ni)
                acc[mi][ni] = __builtin_amdgcn_mfma_f32_16x16x32_bf16(
                    af[mi], bfr[ni], acc[mi][ni], 0, 0, 0);
        // no trailing barrier: next iteration writes the other LDS buffer
    }
#pragma unroll
    for (int mi = 0; mi < 4; ++mi)
#pragma unroll
        for (int ni = 0; ni < 4; ++ni) {
            int r0 = row0 + mi * 16 + quad * 4;
            int c = w * 64 + ni * 16 + l16;
#pragma unroll
            for (int r = 0; r < 4; ++r)
                Cb[(size_t)(r0 + r) * HC + c] = f2bf(acc[mi][ni][r]);
        }
    // fused attention scores (head = w), wave-local
    float as_v[4], ad_v[4];
#pragma unroll
    for (int ni = 0; ni < 4; ++ni) {
        int cl = ni * 16 + l16;
        as_v[ni] = asrc[w * 64 + cl];
        ad_v[ni] = adst[w * 64 + cl];
    }
#pragma unroll
    for (int mi = 0; mi < 4; ++mi)
#pragma unroll
        for (int r = 0; r < 4; ++r) {
            float s = 0.f, d = 0.f;
#pragma unroll
            for (int ni = 0; ni < 4; ++ni) {
                s += acc[mi][ni][r] * as_v[ni];
                d += acc[mi][ni][r] * ad_v[ni];
            }
#pragma unroll
            for (int off = 1; off < 16; off <<= 1) {
                s += __shfl_xor(s, off);
                d += __shfl_xor(d, off);
            }
            if (l16 == 0) {
                int row = row0 + mi * 16 + quad * 4 + r;
                es[(size_t)row * NHEAD + w] = s;
                ed[(size_t)row * NHEAD + w] = d;
            }
        }
}

// ------- softmax + aggregation (layer 1) + BN partial stats ---------------
// 2 nodes/wave, bf16 gather (16B/lane). 16-deep gather unroll (latency probe):
// clamped duplicate slots are same-row L1 hits and w=0 keeps sums exact.
// BN stats from pre-rounding f32 via LDS transpose + non-atomic 2KB partial.
__global__ __launch_bounds__(256) void aggregate_kernel(const unsigned short* __restrict__ h,
                                                        const float* __restrict__ es,
                                                        const float* __restrict__ ed,
                                                        const int* __restrict__ deg,
                                                        const unsigned short* __restrict__ esorted,
                                                        const float* __restrict__ bias,
                                                        unsigned short* __restrict__ outb,
                                                        float* __restrict__ partials) {
    __shared__ float sdata[8][256];
    int tid = threadIdx.x;
    int wave = tid >> 6, lane = tid & 63;
    int half = lane >> 5, l = lane & 31;       // 2 nodes per wave, 32 lanes each
    int nloc = wave * 2 + half;
    int node = blockIdx.x * 8 + nloc;
    int hh = l >> 3;                            // 8 channels/lane -> head = l>>3
    float edv = ed[node * NHEAD + hh];
    int d = deg[node];
    int beg = node * SLOTCAP;
    float dsum = 0.f;
    float a[8] = {0.f, 0.f, 0.f, 0.f, 0.f, 0.f, 0.f, 0.f};
    for (int i = 0; i < d; i += 16) {
        int s[16];
        int4 hv[16];
        float ep[16];
#pragma unroll
        for (int j = 0; j < 16; ++j) {
            int slot = i + j;
            s[j] = esorted[beg + (slot < d ? slot : d - 1)];
        }
#pragma unroll
        for (int j = 0; j < 16; ++j)
            hv[j] = *(const int4*)(h + (size_t)s[j] * HC + l * 8);
#pragma unroll
        for (int j = 0; j < 16; ++j)
            ep[j] = es[s[j] * NHEAD + hh];
#pragma unroll
        for (int j = 0; j < 16; ++j) {
            float e = ep[j] + edv;
            e = e > 0.f ? e : 0.2f * e;
            float w = __expf(e);
            w = (i + j < d) ? w : 0.f;   // adding exact 0.0f: order-identical sums
            dsum += w;
            union { int4 v; unsigned short u[8]; } hu;
            hu.v = hv[j];
#pragma unroll
            for (int k = 0; k < 8; ++k) a[k] += w * bf2f(hu.u[k]);
        }
    }
    float inv = 1.f / (dsum + 1e-16f);
    float4 bv0 = *(const float4*)(bias + l * 8);
    float4 bv1 = *(const float4*)(bias + l * 8 + 4);
    float bb[8] = {bv0.x, bv0.y, bv0.z, bv0.w, bv1.x, bv1.y, bv1.z, bv1.w};
    float ov[8];
    union { int4 v; unsigned short u[8]; } o;
#pragma unroll
    for (int k = 0; k < 8; ++k) {
        ov[k] = a[k] * inv + bb[k];
        o.u[k] = f2bf(ov[k]);
    }
    *(int4*)(outb + (size_t)node * HC + l * 8) = o.v;
    // BN partial stats: transpose via LDS, 256 threads sum 8 nodes each
#pragma unroll
    for (int k = 0; k < 8; ++k) sdata[nloc][l * 8 + k] = ov[k];
    __syncthreads();
    {
        int c = tid;
        float s = 0.f, s2 = 0.f;
#pragma unroll
        for (int n = 0; n < 8; ++n) {
            float v = sdata[n][c];
            s += v; s2 += v * v;
        }
        float* pb = partials + (size_t)blockIdx.x * 512;
        pb[c] = s;
        pb[256 + c] = s2;
    }
}

// ------- layer-2 aggregation + JK max (BN+ELU recompute) + projection ------
__global__ __launch_bounds__(512) void aggregate2_fused(const unsigned short* __restrict__ h,
                                                        const float* __restrict__ es,
                                                        const float* __restrict__ ed,
                                                        const int* __restrict__ deg,
                                                        const unsigned short* __restrict__ esorted,
                                                        const float* __restrict__ bias,
                                                        const unsigned short* __restrict__ h1agg,
                                                        const float* __restrict__ bnsc,
                                                        const unsigned short* __restrict__ linWt,
                                                        const float* __restrict__ linb,
                                                        float* __restrict__ out) {
    __shared__ unsigned short jkS[16 * 264];
    __shared__ unsigned short BsF[64 * 264];
    int tid = threadIdx.x;
    // stage linWt [64][256] -> BsF (512 threads x 32 shorts), overlaps agg
    {
        int n = tid >> 3, k0 = (tid & 7) * 32;
        const int4* src = (const int4*)(linWt + n * 256 + k0);
        int4 v0 = src[0], v1 = src[1], v2 = src[2], v3 = src[3];
        int4* dstp = (int4*)(&BsF[n * 264 + k0]);
        dstp[0] = v0; dstp[1] = v1; dstp[2] = v2; dstp[3] = v3;
    }
    int wave = tid >> 6, lane = tid & 63;
    int half = lane >> 5, l = lane & 31;       // 2 nodes per wave, 32 lanes each
    int nloc = wave * 2 + half;                // 0..15
    int node = blockIdx.x * 16 + nloc;
    int hh = l >> 3;
    float edv = ed[node * NHEAD + hh];
    int d = deg[node];
    int beg = node * SLOTCAP;
    float dsum = 0.f;
    float a[8] = {0.f, 0.f, 0.f, 0.f, 0.f, 0.f, 0.f, 0.f};
    for (int i = 0; i < d; i += 8) {
        int s[8];
        int4 hv[8];
        float ep[8];
#pragma unroll
        for (int j = 0; j < 8; ++j) {
            int slot = i + j;
            s[j] = esorted[beg + (slot < d ? slot : d - 1)];
        }
#pragma unroll
        for (int j = 0; j < 8; ++j)
            hv[j] = *(const int4*)(h + (size_t)s[j] * HC + l * 8);
#pragma unroll
        for (int j = 0; j < 8; ++j)
            ep[j] = es[s[j] * NHEAD + hh];
#pragma unroll
        for (int j = 0; j < 8; ++j) {
            float e = ep[j] + edv;
            e = e > 0.f ? e : 0.2f * e;
            float w = __expf(e);
            w = (i + j < d) ? w : 0.f;
            dsum += w;
            union { int4 v; unsigned short u[8]; } hu;
            hu.v = hv[j];
#pragma unroll
            for (int k = 0; k < 8; ++k) a[k] += w * bf2f(hu.u[k]);
        }
    }
    float inv = 1.f / (dsum + 1e-16f);
    float4 bv0 = *(const float4*)(bias + l * 8);
    float4 bv1 = *(const float4*)(bias + l * 8 + 4);
    float bb[8] = {bv0.x, bv0.y, bv0.z, bv0.w, bv1.x, bv1.y, bv1.z, bv1.w};
    union { int4 v; unsigned short u[8]; } o;
    {
        union { int4 v; unsigned short u[8]; } h1u;
        h1u.v = *(const int4*)(h1agg + (size_t)node * HC + l * 8);
        float4 s0 = *(const float4*)(bnsc + l * 8);
        float4 s1 = *(const float4*)(bnsc + l * 8 + 4);
        float4 t0 = *(const float4*)(bnsc + HC + l * 8);
        float4 t1 = *(const float4*)(bnsc + HC + l * 8 + 4);
        float scv[8] = {s0.x, s0.y, s0.z, s0.w, s1.x, s1.y, s1.z, s1.w};
        float shv[8] = {t0.x, t0.y, t0.z, t0.w, t1.x, t1.y, t1.z, t1.w};
#pragma unroll
        for (int k = 0; k < 8; ++k) {
            float v = bf2f(h1u.u[k]) * scv[k] + shv[k];
            v = v > 0.f ? v : (__expf(v) - 1.f);
            o.u[k] = f2bf(fmaxf(v, a[k] * inv + bb[k]));
        }
    }
    *(int4*)(&jkS[nloc * 264 + l * 8]) = o.v;
    __syncthreads();
    // GEMM phase: 16x256 @ 256x64 on waves 0..3 (N-tile = wave), 8 MFMAs each
    if (wave < 4) {
        int quad = lane >> 4, l16 = lane & 15;
        f32x4 acc = (f32x4){0.f, 0.f, 0.f, 0.f};
#pragma unroll
        for (int kc = 0; kc < HC; kc += 32) {
            bf16x8 af = *(const bf16x8*)(&jkS[l16 * 264 + kc + quad * 8]);
            bf16x8 bfr = *(const bf16x8*)(&BsF[(wave * 16 + l16) * 264 + kc + quad * 8]);
            acc = __builtin_amdgcn_mfma_f32_16x16x32_bf16(af, bfr, acc, 0, 0, 0);
        }
        int row0 = blockIdx.x * 16 + quad * 4;
        int c = wave * 16 + l16;
        float bc = linb[c];
#pragma unroll
        for (int r = 0; r < 4; ++r)
            out[(size_t)(row0 + r) * NOUT + c] = acc[r] + bc;
    }
}

// ---------------- BN: reduce per-block partials + ticket finalize ----------
// 40 blocks, coalesced f32 reads (10.2MB), 20K atomics @ 40-way contention.
__global__ __launch_bounds__(256) void bn_reduce_kernel(const float* __restrict__ partials,
                                                        float* __restrict__ acc,
                                                        const float* __restrict__ gamma,
                                                        const float* __restrict__ beta,
                                                        float* __restrict__ sc,
                                                        int* __restrict__ ticket) {
    int t = threadIdx.x;
    const int per = (N_NODES / 8) / BN_RBLK;   // 125
    int b0 = blockIdx.x * per;
    float A = 0.f, B = 0.f;
    for (int b = b0; b < b0 + per; ++b) {
        A += partials[(size_t)b * 512 + t];
        B += partials[(size_t)b * 512 + 256 + t];
    }
    atomicAdd(&acc[t], A);
    atomicAdd(&acc[HC + t], B);
    __threadfence();
    __syncthreads();
    __shared__ int is_last;
    if (t == 0) is_last = (atomicAdd(ticket, 1) == BN_RBLK - 1);
    __syncthreads();
    if (is_last) {
        float sum = atomicAdd(&acc[t], 0.f);   // coherent readback
        float sq  = atomicAdd(&acc[HC + t], 0.f);
        float mean = sum * (1.f / N_NODES);
        float var = sq * (1.f / N_NODES) - mean * mean;
        float inv = rsqrtf(var + 1e-5f);
        float scale = gamma[t] * inv;
        sc[t] = scale;
        sc[HC + t] = beta[t] - mean * scale;
    }
}

extern "C" void kernel_launch(void* const* d_in, const int* in_sizes, int n_in,
                              void* d_out, int out_size, void* d_ws, size_t ws_size,
                              hipStream_t stream) {
    const float* x      = (const float*)d_in[0];
    const int*   ei     = (const int*)d_in[1];
    const float* W1     = (const float*)d_in[2];
    const float* a1_src = (const float*)d_in[3];
    const float* a1_dst = (const float*)d_in[4];
    const float* b1     = (const float*)d_in[5];
    const float* bn_g   = (const float*)d_in[6];
    const float* bn_b   = (const float*)d_in[7];
    const float* W2     = (const float*)d_in[8];
    const float* a2_src = (const float*)d_in[9];
    const float* a2_dst = (const float*)d_in[10];
    const float* b2     = (const float*)d_in[11];
    const float* linW   = (const float*)d_in[12];
    const float* linb   = (const float*)d_in[13];
    float* out = (float*)d_out;

    char* ws = (char*)d_ws;
    const size_t NHC_BF = (size_t)N_NODES * HC * 2;   // 20.48 MB
    unsigned short* hpre_b  = (unsigned short*)(ws);                  // h_pre (both layers)
    unsigned short* h1agg_b = (unsigned short*)(ws + NHC_BF);         // agg1 (pre-BN)
    float* partials = (float*)(ws + 2 * NHC_BF);                      // [5000][512] f32
    char* p = ws + 4 * NHC_BF;
    unsigned short* W1t   = (unsigned short*)p; p += (size_t)F_IN * HC * 2;
    unsigned short* W2t   = (unsigned short*)p; p += (size_t)HC * HC * 2;
    unsigned short* linWt = (unsigned short*)p; p += (size_t)HC * NOUT * 2;
    float* e_src   = (float*)p;  p += (size_t)N_NODES * NHEAD * 4;
    float* e_dst   = (float*)p;  p += (size_t)N_NODES * NHEAD * 4;
    // zero region: cursor + ticket (40004 ints)
    int*   cursor  = (int*)p;    p += (size_t)N_NODES * 4;
    int*   ticket  = (int*)p;    p += 4 * 4;
    unsigned short* esorted = (unsigned short*)p; p += (size_t)N_NODES * SLOTCAP * 2;  // 3.2 MB
    float* bnacc   = (float*)p;  p += 2 * HC * 4;
    float* bnsc    = (float*)p;  p += 2 * HC * 4;

    // 1. prep: weight converts + zero cursor/ticket/bnacc
    prep_kernel<<<489, 256, 0, stream>>>(W1, W2, linW, W1t, W2t, linWt, cursor, bnacc);

    // 2. layer-1 wide GEMM (f32 A) + fused scores + fused CSR scatter (u16)
    gemm_wide<1, 1><<<N_NODES / 64 + (N_EDGES + 255) / 256, 256, 0, stream>>>(
        x, W1t, nullptr, hpre_b, a1_src, a1_dst, e_src, e_dst, F_IN,
        ei, cursor, esorted);

    // 3. aggregate 1 (+ BN partial stats from pre-rounding f32), 16-deep MLP
    aggregate_kernel<<<N_NODES / 8, 256, 0, stream>>>(
        hpre_b, e_src, e_dst, cursor, esorted, b1, h1agg_b, partials);

    // 4. BN partial reduce + finalize (ticket-fused, 40 blocks)
    bn_reduce_kernel<<<BN_RBLK, 256, 0, stream>>>(partials, bnacc, bn_g, bn_b,
                                                  bnsc, ticket);

    // 5. layer-2 wide GEMM (BN+ELU fused into staging) + scores
    gemm_wide<3, 0><<<N_NODES / 64, 256, 0, stream>>>(
        h1agg_b, W2t, bnsc, hpre_b, a2_src, a2_dst, e_src, e_dst, HC,
        nullptr, nullptr, nullptr);

    // 6. aggregate 2 + JK max (BN+ELU recompute) + fused final projection
    aggregate2_fused<<<N_NODES / 16, 512, 0, stream>>>(
        hpre_b, e_src, e_dst, cursor, esorted, b2, h1agg_b, bnsc, linWt, linb, out);
}